// Round 3
// baseline (1042.346 us; speedup 1.0000x reference)
//
#include <hip/hip_runtime.h>

#define B_ 8
#define N_ 1024
#define C_ 768
#define H_ 12
#define D_ 64
#define SCALE_ 0.125f

typedef _Float16 v8h __attribute__((ext_vector_type(8)));
typedef float v4f __attribute__((ext_vector_type(4)));

__device__ __forceinline__ void gload_lds16(const void* g, void* l) {
    __builtin_amdgcn_global_load_lds((const __attribute__((address_space(1))) void*)g,
                                     (__attribute__((address_space(3))) void*)l, 16, 0, 0);
}

// ---------------------------------------------------------------------------
// cast fp32 -> fp16, 8 elems/thread
// ---------------------------------------------------------------------------
__global__ __launch_bounds__(256) void cast_f2h(const float* __restrict__ src,
                                                _Float16* __restrict__ dst, int n8) {
    const int i = blockIdx.x * 256 + threadIdx.x;
    if (i < n8) {
        const v4f a = *(const v4f*)&src[(size_t)i * 8];
        const v4f b = *(const v4f*)&src[(size_t)i * 8 + 4];
        v8h o;
        o[0] = (_Float16)a[0]; o[1] = (_Float16)a[1]; o[2] = (_Float16)a[2]; o[3] = (_Float16)a[3];
        o[4] = (_Float16)b[0]; o[5] = (_Float16)b[1]; o[6] = (_Float16)b[2]; o[7] = (_Float16)b[3];
        *(v8h*)&dst[(size_t)i * 8] = o;
    }
}

// ---------------------------------------------------------------------------
// K1: qkv = xh[8192,768] @ wqh[2304,768]^T via MFMA. 128x128 tile, BK=32,
// double-buffered LDS, single barrier per K-step. (unchanged this round)
// ---------------------------------------------------------------------------
__global__ __launch_bounds__(256) void gemm_qkv(const _Float16* __restrict__ X,
                                                const _Float16* __restrict__ W,
                                                _Float16* __restrict__ qh,
                                                _Float16* __restrict__ kh,
                                                _Float16* __restrict__ vth) {
    __shared__ _Float16 As[2 * 128 * 32];
    __shared__ _Float16 Bs[2 * 128 * 32];
    const int t = threadIdx.x;
    const int w = t >> 6, l = t & 63;
    const int q4 = l >> 4, c0 = l & 15;
    const int wm = w & 1, wn = w >> 1;
    const int m0 = blockIdx.x * 128, n0 = blockIdx.y * 128;
    const int sc8 = (t & 3) * 8;
    const int srow = t >> 2;
    v4f acc[4][4] = {};
    #pragma unroll
    for (int i = 0; i < 2; ++i) {
        const int row = i * 64 + srow;
        gload_lds16(&X[(size_t)(m0 + row) * C_ + sc8], &As[(i * 256 + t) * 8]);
        gload_lds16(&W[(size_t)(n0 + row) * C_ + sc8], &Bs[(i * 256 + t) * 8]);
    }
    __syncthreads();
    int cb = 0;
    for (int k0 = 0; k0 < C_; k0 += 32, cb ^= 1) {
        if (k0 + 32 < C_) {
            const int nb = cb ^ 1;
            #pragma unroll
            for (int i = 0; i < 2; ++i) {
                const int row = i * 64 + srow;
                gload_lds16(&X[(size_t)(m0 + row) * C_ + k0 + 32 + sc8],
                            &As[(nb * 512 + i * 256 + t) * 8]);
                gload_lds16(&W[(size_t)(n0 + row) * C_ + k0 + 32 + sc8],
                            &Bs[(nb * 512 + i * 256 + t) * 8]);
            }
        }
        v8h a[4], b[4];
        #pragma unroll
        for (int mi = 0; mi < 4; ++mi)
            a[mi] = *(const v8h*)&As[cb * 4096 + (wm * 64 + mi * 16 + c0) * 32 + q4 * 8];
        #pragma unroll
        for (int ni = 0; ni < 4; ++ni)
            b[ni] = *(const v8h*)&Bs[cb * 4096 + (wn * 64 + ni * 16 + c0) * 32 + q4 * 8];
        #pragma unroll
        for (int mi = 0; mi < 4; ++mi)
            #pragma unroll
            for (int ni = 0; ni < 4; ++ni)
                acc[mi][ni] = __builtin_amdgcn_mfma_f32_16x16x32_f16(a[mi], b[ni], acc[mi][ni], 0, 0, 0);
        __syncthreads();
    }
    const int which = n0 / C_;
    const int nbase = n0 % C_;
    #pragma unroll
    for (int ni = 0; ni < 4; ++ni) {
        const int n = nbase + wn * 64 + ni * 16 + c0;
        const int h = n >> 6, d = n & 63;
        #pragma unroll
        for (int mi = 0; mi < 4; ++mi) {
            #pragma unroll
            for (int r = 0; r < 4; ++r) {
                const int m = m0 + wm * 64 + mi * 16 + q4 * 4 + r;
                const int b = m >> 10, nn = m & 1023;
                const _Float16 val = (_Float16)acc[mi][ni][r];
                if (which == 0)
                    qh[((size_t)(b * H_ + h) * N_ + nn) * D_ + d] = val;
                else if (which == 1)
                    kh[((size_t)(b * H_ + h) * N_ + nn) * D_ + d] = val;
                else
                    vth[((size_t)(b * H_ + h) * D_ + d) * N_ + nn] = val;
            }
        }
    }
}

// ---------------------------------------------------------------------------
// K2: fused attention, 3-barrier structure.
// Block = 32 q-rows x one (b,h). Grid (32, 96), 512 thr = 8 waves (2 wg x 4 wl).
// K/V per head = 256 KB, L2-resident (32 blocks share it) -> read MFMA
// B-fragments DIRECTLY from global (16 rows x 64B fully-used sectors per
// instr); no K/V LDS staging, no staging barriers. QK^T: 0 barriers.
// Softmax: 2 barriers (cross-wave reduce). P handoff: fp32 attn stored
// straight from registers (nontemporal dwords, 4x64B sectors/instr), P cast
// fp16 into one padded LDS buffer (stride 1032 halfs -> 2-way bank alias =
// free), ONE barrier. PV: 0 barriers; A-frags ds_read_b128 from Ph, V direct
// from global; O split into 2 accumulators to break the dependent MFMA chain.
// ---------------------------------------------------------------------------
__global__ __launch_bounds__(512, 4) void attn_fused(const _Float16* __restrict__ qh,
                                                     const _Float16* __restrict__ kh,
                                                     const _Float16* __restrict__ vth,
                                                     float* __restrict__ attn,
                                                     _Float16* __restrict__ oah) {
    __shared__ _Float16 Ph[32 * 1032];          // P fp16, padded stride (66 KB)
    __shared__ float redm[128], reds[128];
    const int t = threadIdx.x;
    const int w = t >> 6, l = t & 63;
    const int q4 = l >> 4, c0 = l & 15;
    const int wg = w >> 2, wl = w & 3;          // q-row group / k-col group
    const int mt = blockIdx.x, bh = blockIdx.y;
    const size_t qkbase = (size_t)bh * N_ * D_;
    const size_t vtbase = (size_t)bh * D_ * N_;

    // Q A-frags straight from global (L2)
    const _Float16* qp = &qh[qkbase + (size_t)(mt * 32 + wg * 16 + c0) * D_ + q4 * 8];
    const v8h a0 = *(const v8h*)qp;
    const v8h a1 = *(const v8h*)(qp + 32);

    v4f S[16];
    #pragma unroll
    for (int i = 0; i < 16; ++i) S[i] = (v4f){0.f, 0.f, 0.f, 0.f};

    // ---- QK^T: B-frags direct from L2, zero barriers ----
    const _Float16* kp = &kh[qkbase + (size_t)(wl * 16 + c0) * D_ + q4 * 8];
    #pragma unroll 2
    for (int c = 0; c < 16; ++c) {
        const v8h b0 = *(const v8h*)(kp + (size_t)c * 64 * D_);
        const v8h b1 = *(const v8h*)(kp + (size_t)c * 64 * D_ + 32);
        const v4f acc = __builtin_amdgcn_mfma_f32_16x16x32_f16(a0, b0, S[c], 0, 0, 0);
        S[c] = __builtin_amdgcn_mfma_f32_16x16x32_f16(a1, b1, acc, 0, 0, 0);
    }

    // ---- softmax (fp32): row = wg*16 + q4*4 + r; cols spread over c0 & wl ----
    float mrow[4] = {-1e30f, -1e30f, -1e30f, -1e30f};
    #pragma unroll
    for (int kt = 0; kt < 16; ++kt)
        #pragma unroll
        for (int r = 0; r < 4; ++r) mrow[r] = fmaxf(mrow[r], S[kt][r]);
    #pragma unroll
    for (int r = 0; r < 4; ++r) {
        #pragma unroll
        for (int mask = 8; mask; mask >>= 1)
            mrow[r] = fmaxf(mrow[r], __shfl_xor(mrow[r], mask, 16));
    }
    if (c0 == 0) {
        #pragma unroll
        for (int r = 0; r < 4; ++r) redm[w * 16 + q4 * 4 + r] = mrow[r];
    }
    __syncthreads();
    #pragma unroll
    for (int r = 0; r < 4; ++r) {
        const int base = wg * 64 + q4 * 4 + r;
        mrow[r] = fmaxf(fmaxf(redm[base], redm[base + 16]),
                        fmaxf(redm[base + 32], redm[base + 48]));
    }
    float srow[4] = {0.f, 0.f, 0.f, 0.f};
    #pragma unroll
    for (int kt = 0; kt < 16; ++kt)
        #pragma unroll
        for (int r = 0; r < 4; ++r) {
            const float e = __expf((S[kt][r] - mrow[r]) * SCALE_);
            S[kt][r] = e;
            srow[r] += e;
        }
    #pragma unroll
    for (int r = 0; r < 4; ++r) {
        #pragma unroll
        for (int mask = 8; mask; mask >>= 1) srow[r] += __shfl_xor(srow[r], mask, 16);
    }
    if (c0 == 0) {
        #pragma unroll
        for (int r = 0; r < 4; ++r) reds[w * 16 + q4 * 4 + r] = srow[r];
    }
    __syncthreads();
    float inv[4];
    #pragma unroll
    for (int r = 0; r < 4; ++r) {
        const int base = wg * 64 + q4 * 4 + r;
        inv[r] = 1.0f / (reds[base] + reds[base + 16] + reds[base + 32] + reds[base + 48]);
    }

    // ---- attn store direct from regs + P fp16 -> LDS, ONE barrier ----
    #pragma unroll
    for (int r = 0; r < 4; ++r) {
        const int row = wg * 16 + q4 * 4 + r;
        float* ab = &attn[((size_t)bh * N_ + mt * 32 + row) * N_ + wl * 16 + c0];
        _Float16* pb = &Ph[row * 1032 + wl * 16 + c0];
        #pragma unroll
        for (int kt = 0; kt < 16; ++kt) {
            const float p = S[kt][r] * inv[r];
            __builtin_nontemporal_store(p, ab + kt * 64);
            pb[kt * 64] = (_Float16)p;
        }
    }
    __syncthreads();

    // ---- PV: A-frags from Ph (LDS), V direct from L2, zero barriers ----
    v4f O0 = {0.f, 0.f, 0.f, 0.f}, O1 = {0.f, 0.f, 0.f, 0.f};
    const _Float16* vp = &vth[vtbase + (size_t)(wl * 16 + c0) * N_ + q4 * 8];
    const _Float16* pf = &Ph[(wg * 16 + c0) * 1032 + q4 * 8];
    #pragma unroll 2
    for (int s = 0; s < 16; ++s) {
        const v8h af0 = *(const v8h*)(pf + s * 64);
        const v8h bf0 = *(const v8h*)(vp + s * 64);
        const v8h af1 = *(const v8h*)(pf + s * 64 + 32);
        const v8h bf1 = *(const v8h*)(vp + s * 64 + 32);
        O0 = __builtin_amdgcn_mfma_f32_16x16x32_f16(af0, bf0, O0, 0, 0, 0);
        O1 = __builtin_amdgcn_mfma_f32_16x16x32_f16(af1, bf1, O1, 0, 0, 0);
    }
    const int b = bh / H_, h = bh % H_;
    #pragma unroll
    for (int r = 0; r < 4; ++r)
        oah[((size_t)b * N_ + mt * 32 + wg * 16 + q4 * 4 + r) * C_ + h * D_ + wl * 16 + c0] =
            (_Float16)(O0[r] + O1[r]);
}

// ---------------------------------------------------------------------------
// K4: out = oah[8192,768] @ wph[768,768]^T + bias, fp32 out (nontemporal).
// (unchanged this round)
// ---------------------------------------------------------------------------
__global__ __launch_bounds__(256) void gemm_proj(const _Float16* __restrict__ X,
                                                 const _Float16* __restrict__ W,
                                                 const float* __restrict__ Bias,
                                                 float* __restrict__ out) {
    __shared__ _Float16 As[2 * 128 * 32];
    __shared__ _Float16 Bs[2 * 128 * 32];
    const int t = threadIdx.x;
    const int w = t >> 6, l = t & 63;
    const int q4 = l >> 4, c0 = l & 15;
    const int wm = w & 1, wn = w >> 1;
    const int m0 = blockIdx.x * 128, n0 = blockIdx.y * 128;
    const int sc8 = (t & 3) * 8;
    const int srow = t >> 2;
    v4f acc[4][4] = {};
    #pragma unroll
    for (int i = 0; i < 2; ++i) {
        const int row = i * 64 + srow;
        gload_lds16(&X[(size_t)(m0 + row) * C_ + sc8], &As[(i * 256 + t) * 8]);
        gload_lds16(&W[(size_t)(n0 + row) * C_ + sc8], &Bs[(i * 256 + t) * 8]);
    }
    __syncthreads();
    int cb = 0;
    for (int k0 = 0; k0 < C_; k0 += 32, cb ^= 1) {
        if (k0 + 32 < C_) {
            const int nb = cb ^ 1;
            #pragma unroll
            for (int i = 0; i < 2; ++i) {
                const int row = i * 64 + srow;
                gload_lds16(&X[(size_t)(m0 + row) * C_ + k0 + 32 + sc8],
                            &As[(nb * 512 + i * 256 + t) * 8]);
                gload_lds16(&W[(size_t)(n0 + row) * C_ + k0 + 32 + sc8],
                            &Bs[(nb * 512 + i * 256 + t) * 8]);
            }
        }
        v8h a[4], b[4];
        #pragma unroll
        for (int mi = 0; mi < 4; ++mi)
            a[mi] = *(const v8h*)&As[cb * 4096 + (wm * 64 + mi * 16 + c0) * 32 + q4 * 8];
        #pragma unroll
        for (int ni = 0; ni < 4; ++ni)
            b[ni] = *(const v8h*)&Bs[cb * 4096 + (wn * 64 + ni * 16 + c0) * 32 + q4 * 8];
        #pragma unroll
        for (int mi = 0; mi < 4; ++mi)
            #pragma unroll
            for (int ni = 0; ni < 4; ++ni)
                acc[mi][ni] = __builtin_amdgcn_mfma_f32_16x16x32_f16(a[mi], b[ni], acc[mi][ni], 0, 0, 0);
        __syncthreads();
    }
    #pragma unroll
    for (int ni = 0; ni < 4; ++ni) {
        const int n = n0 + wn * 64 + ni * 16 + c0;
        const float bias = Bias[n];
        #pragma unroll
        for (int mi = 0; mi < 4; ++mi) {
            #pragma unroll
            for (int r = 0; r < 4; ++r) {
                const int m = m0 + wm * 64 + mi * 16 + q4 * 4 + r;
                __builtin_nontemporal_store(acc[mi][ni][r] + bias, &out[(size_t)m * C_ + n]);
            }
        }
    }
}

extern "C" void kernel_launch(void* const* d_in, const int* in_sizes, int n_in,
                              void* d_out, int out_size, void* d_ws, size_t ws_size,
                              hipStream_t stream) {
    const float* x      = (const float*)d_in[0];
    const float* w_qkv  = (const float*)d_in[1];
    const float* w_proj = (const float*)d_in[2];
    const float* b_proj = (const float*)d_in[3];

    float* out  = (float*)d_out;                 // [8,1024,768]
    float* attn = out + (size_t)B_ * N_ * C_;    // [8,12,1024,1024]

    const size_t NX  = (size_t)B_ * N_ * C_;
    const size_t NWQ = (size_t)3 * C_ * C_;
    const size_t NWP = (size_t)C_ * C_;
    _Float16* xh  = (_Float16*)d_ws;
    _Float16* wqh = xh + NX;
    _Float16* wph = wqh + NWQ;
    _Float16* qh  = wph + NWP;
    _Float16* kh  = qh + NX;
    _Float16* vth = kh + NX;
    _Float16* oah = vth + NX;

    cast_f2h<<<dim3((int)(NX / 8 / 256)), 256, 0, stream>>>(x, xh, (int)(NX / 8));
    cast_f2h<<<dim3((int)(NWQ / 8 / 256)), 256, 0, stream>>>(w_qkv, wqh, (int)(NWQ / 8));
    cast_f2h<<<dim3((int)(NWP / 8 / 256)), 256, 0, stream>>>(w_proj, wph, (int)(NWP / 8));

    gemm_qkv  <<<dim3(64, 18), 256, 0, stream>>>(xh, wqh, qh, kh, vth);
    attn_fused<<<dim3(32, 96), 512, 0, stream>>>(qh, kh, vth, attn, oah);
    gemm_proj <<<dim3(64, 6), 256, 0, stream>>>(oah, wph, b_proj, out);
}

// Round 4
// 918.136 us; speedup vs baseline: 1.1353x; 1.1353x over previous
//
#include <hip/hip_runtime.h>

#define B_ 8
#define N_ 1024
#define C_ 768
#define H_ 12
#define D_ 64
#define SCALE_ 0.125f

typedef _Float16 v8h __attribute__((ext_vector_type(8)));
typedef float v4f __attribute__((ext_vector_type(4)));

__device__ __forceinline__ void gload_lds16(const void* g, void* l) {
    __builtin_amdgcn_global_load_lds((const __attribute__((address_space(1))) void*)g,
                                     (__attribute__((address_space(3))) void*)l, 16, 0, 0);
}

// raw workgroup barrier with scheduling fences (no vmcnt drain)
__device__ __forceinline__ void raw_sync() {
    __builtin_amdgcn_sched_barrier(0);
    __builtin_amdgcn_s_barrier();
    __builtin_amdgcn_sched_barrier(0);
}
__device__ __forceinline__ void lgkm0() {
    asm volatile("s_waitcnt lgkmcnt(0)" ::: "memory");
    __builtin_amdgcn_sched_barrier(0);
}

// ---------------------------------------------------------------------------
// cast fp32 -> fp16, 8 elems/thread
// ---------------------------------------------------------------------------
__global__ __launch_bounds__(256) void cast_f2h(const float* __restrict__ src,
                                                _Float16* __restrict__ dst, int n8) {
    const int i = blockIdx.x * 256 + threadIdx.x;
    if (i < n8) {
        const v4f a = *(const v4f*)&src[(size_t)i * 8];
        const v4f b = *(const v4f*)&src[(size_t)i * 8 + 4];
        v8h o;
        o[0] = (_Float16)a[0]; o[1] = (_Float16)a[1]; o[2] = (_Float16)a[2]; o[3] = (_Float16)a[3];
        o[4] = (_Float16)b[0]; o[5] = (_Float16)b[1]; o[6] = (_Float16)b[2]; o[7] = (_Float16)b[3];
        *(v8h*)&dst[(size_t)i * 8] = o;
    }
}

// ---------------------------------------------------------------------------
// K1: qkv = xh[8192,768] @ wqh[2304,768]^T via MFMA. 128x128 tile, BK=32,
// double-buffered LDS, single barrier per K-step. (unchanged)
// ---------------------------------------------------------------------------
__global__ __launch_bounds__(256) void gemm_qkv(const _Float16* __restrict__ X,
                                                const _Float16* __restrict__ W,
                                                _Float16* __restrict__ qh,
                                                _Float16* __restrict__ kh,
                                                _Float16* __restrict__ vth) {
    __shared__ _Float16 As[2 * 128 * 32];
    __shared__ _Float16 Bs[2 * 128 * 32];
    const int t = threadIdx.x;
    const int w = t >> 6, l = t & 63;
    const int q4 = l >> 4, c0 = l & 15;
    const int wm = w & 1, wn = w >> 1;
    const int m0 = blockIdx.x * 128, n0 = blockIdx.y * 128;
    const int sc8 = (t & 3) * 8;
    const int srow = t >> 2;
    v4f acc[4][4] = {};
    #pragma unroll
    for (int i = 0; i < 2; ++i) {
        const int row = i * 64 + srow;
        gload_lds16(&X[(size_t)(m0 + row) * C_ + sc8], &As[(i * 256 + t) * 8]);
        gload_lds16(&W[(size_t)(n0 + row) * C_ + sc8], &Bs[(i * 256 + t) * 8]);
    }
    __syncthreads();
    int cb = 0;
    for (int k0 = 0; k0 < C_; k0 += 32, cb ^= 1) {
        if (k0 + 32 < C_) {
            const int nb = cb ^ 1;
            #pragma unroll
            for (int i = 0; i < 2; ++i) {
                const int row = i * 64 + srow;
                gload_lds16(&X[(size_t)(m0 + row) * C_ + k0 + 32 + sc8],
                            &As[(nb * 512 + i * 256 + t) * 8]);
                gload_lds16(&W[(size_t)(n0 + row) * C_ + k0 + 32 + sc8],
                            &Bs[(nb * 512 + i * 256 + t) * 8]);
            }
        }
        v8h a[4], b[4];
        #pragma unroll
        for (int mi = 0; mi < 4; ++mi)
            a[mi] = *(const v8h*)&As[cb * 4096 + (wm * 64 + mi * 16 + c0) * 32 + q4 * 8];
        #pragma unroll
        for (int ni = 0; ni < 4; ++ni)
            b[ni] = *(const v8h*)&Bs[cb * 4096 + (wn * 64 + ni * 16 + c0) * 32 + q4 * 8];
        #pragma unroll
        for (int mi = 0; mi < 4; ++mi)
            #pragma unroll
            for (int ni = 0; ni < 4; ++ni)
                acc[mi][ni] = __builtin_amdgcn_mfma_f32_16x16x32_f16(a[mi], b[ni], acc[mi][ni], 0, 0, 0);
        __syncthreads();
    }
    const int which = n0 / C_;
    const int nbase = n0 % C_;
    #pragma unroll
    for (int ni = 0; ni < 4; ++ni) {
        const int n = nbase + wn * 64 + ni * 16 + c0;
        const int h = n >> 6, d = n & 63;
        #pragma unroll
        for (int mi = 0; mi < 4; ++mi) {
            #pragma unroll
            for (int r = 0; r < 4; ++r) {
                const int m = m0 + wm * 64 + mi * 16 + q4 * 4 + r;
                const int b = m >> 10, nn = m & 1023;
                const _Float16 val = (_Float16)acc[mi][ni][r];
                if (which == 0)
                    qh[((size_t)(b * H_ + h) * N_ + nn) * D_ + d] = val;
                else if (which == 1)
                    kh[((size_t)(b * H_ + h) * N_ + nn) * D_ + d] = val;
                else
                    vth[((size_t)(b * H_ + h) * D_ + d) * N_ + nn] = val;
            }
        }
    }
}

// ---------------------------------------------------------------------------
// K2: fused attention — direct-L2 loads + bank-clean LDS slab handoff.
// Block = 32 q-rows x one (b,h). 1-D grid 3072 with XCD swizzle: each XCD
// owns 12 whole heads -> K/V fetched from HBM once per head (~24 MB total).
// QK^T: K B-frags direct from L2, 0 barriers. Softmax: 2 barriers.
// Handoff/PV: 8 slabs x 128 cols, Ps fp32 [2][32][132] double-buffered
// (132 % 32 == 4 -> 2-way bank alias = free on writes, v4f store-reads, and
// PV A-frag reads); attn stored as v4f with 16 contiguous lanes = full 128B
// lines (NO write-allocate — round 3's 4x write inflation came from partial-
// line scalar stores). V B-frags direct from L2. 1 LDS-only barrier/slab.
// ---------------------------------------------------------------------------
__global__ __launch_bounds__(512, 4) void attn_fused(const _Float16* __restrict__ qh,
                                                     const _Float16* __restrict__ kh,
                                                     const _Float16* __restrict__ vth,
                                                     float* __restrict__ attn,
                                                     _Float16* __restrict__ oah) {
    __shared__ float Ps[2 * 32 * 132];          // 33.8 KB
    __shared__ float redm[128], reds[128];
    const int t = threadIdx.x;
    const int w = t >> 6, l = t & 63;
    const int q4 = l >> 4, c0 = l & 15;
    const int wg = w >> 2, wl = w & 3;          // q-row group / k-col group
    // XCD-aware swizzle: lin = xcd + 8*idx; xcd owns heads [xcd*12, xcd*12+12)
    const int lin = blockIdx.x;
    const int xcd = lin & 7;
    const int idx = lin >> 3;
    const int bh  = xcd * 12 + (idx >> 5);
    const int mt  = idx & 31;
    const size_t qkbase = (size_t)bh * N_ * D_;
    const size_t vtbase = (size_t)bh * D_ * N_;

    // Q A-frags straight from global (L2)
    const _Float16* qp = &qh[qkbase + (size_t)(mt * 32 + wg * 16 + c0) * D_ + q4 * 8];
    const v8h a0 = *(const v8h*)qp;
    const v8h a1 = *(const v8h*)(qp + 32);

    v4f S[16];
    #pragma unroll
    for (int i = 0; i < 16; ++i) S[i] = (v4f){0.f, 0.f, 0.f, 0.f};

    // ---- QK^T: B-frags direct from L2, zero barriers ----
    const _Float16* kp = &kh[qkbase + (size_t)(wl * 16 + c0) * D_ + q4 * 8];
    #pragma unroll 2
    for (int c = 0; c < 16; ++c) {
        const v8h b0 = *(const v8h*)(kp + (size_t)c * 64 * D_);
        const v8h b1 = *(const v8h*)(kp + (size_t)c * 64 * D_ + 32);
        const v4f acc = __builtin_amdgcn_mfma_f32_16x16x32_f16(a0, b0, S[c], 0, 0, 0);
        S[c] = __builtin_amdgcn_mfma_f32_16x16x32_f16(a1, b1, acc, 0, 0, 0);
    }

    // ---- softmax (fp32): row = wg*16 + q4*4 + r; cols spread over c0 & wl ----
    float mrow[4] = {-1e30f, -1e30f, -1e30f, -1e30f};
    #pragma unroll
    for (int kt = 0; kt < 16; ++kt)
        #pragma unroll
        for (int r = 0; r < 4; ++r) mrow[r] = fmaxf(mrow[r], S[kt][r]);
    #pragma unroll
    for (int r = 0; r < 4; ++r) {
        #pragma unroll
        for (int mask = 8; mask; mask >>= 1)
            mrow[r] = fmaxf(mrow[r], __shfl_xor(mrow[r], mask, 16));
    }
    if (c0 == 0) {
        #pragma unroll
        for (int r = 0; r < 4; ++r) redm[w * 16 + q4 * 4 + r] = mrow[r];
    }
    __syncthreads();
    #pragma unroll
    for (int r = 0; r < 4; ++r) {
        const int base = wg * 64 + q4 * 4 + r;
        mrow[r] = fmaxf(fmaxf(redm[base], redm[base + 16]),
                        fmaxf(redm[base + 32], redm[base + 48]));
    }
    float srow[4] = {0.f, 0.f, 0.f, 0.f};
    #pragma unroll
    for (int kt = 0; kt < 16; ++kt)
        #pragma unroll
        for (int r = 0; r < 4; ++r) {
            const float e = __expf((S[kt][r] - mrow[r]) * SCALE_);
            S[kt][r] = e;
            srow[r] += e;
        }
    #pragma unroll
    for (int r = 0; r < 4; ++r) {
        #pragma unroll
        for (int mask = 8; mask; mask >>= 1) srow[r] += __shfl_xor(srow[r], mask, 16);
    }
    if (c0 == 0) {
        #pragma unroll
        for (int r = 0; r < 4; ++r) reds[w * 16 + q4 * 4 + r] = srow[r];
    }
    __syncthreads();
    float inv[4];
    #pragma unroll
    for (int r = 0; r < 4; ++r) {
        const int base = wg * 64 + q4 * 4 + r;
        inv[r] = 1.0f / (reds[base] + reds[base + 16] + reds[base + 32] + reds[base + 48]);
    }

    // prologue: slab 0 into buf 0
    #pragma unroll
    for (int kt2 = 0; kt2 < 2; ++kt2)
        #pragma unroll
        for (int r = 0; r < 4; ++r)
            Ps[(wg * 16 + q4 * 4 + r) * 132 + kt2 * 64 + wl * 16 + c0] = S[kt2][r] * inv[r];
    lgkm0();
    raw_sync();

    // ---- 8 slabs x 128 cols: full-line attn stores + PV, 1 barrier/slab ----
    v4f O0 = {0.f, 0.f, 0.f, 0.f}, O1 = {0.f, 0.f, 0.f, 0.f};
    const int arow = t >> 4, acol = (t & 15) * 4;
    float* attn_base = &attn[((size_t)bh * N_ + mt * 32 + arow) * N_ + acol];
    const _Float16* vp = &vth[vtbase + (size_t)(wl * 16 + c0) * N_ + q4 * 8];
    const int afrow = (wg * 16 + c0) * 132;
    for (int s = 0; s < 8; ++s) {
        const int pb = (s & 1) * 4224;
        // coalesced nontemporal attn stores (full 128B lines)
        const v4f pv0 = *(const v4f*)&Ps[pb + arow * 132 + acol];
        const v4f pv1 = *(const v4f*)&Ps[pb + arow * 132 + acol + 64];
        __builtin_nontemporal_store(pv0, (v4f*)(attn_base + s * 128));
        __builtin_nontemporal_store(pv1, (v4f*)(attn_base + s * 128 + 64));
        // PV: A-frags from Ps (cvt fp16), V B-frags direct from L2
        #pragma unroll
        for (int kk = 0; kk < 4; ++kk) {
            const float* pp = &Ps[pb + afrow + kk * 32 + q4 * 8];
            const v4f p0 = *(const v4f*)pp;
            const v4f p1 = *(const v4f*)(pp + 4);
            v8h af;
            af[0] = (_Float16)p0[0]; af[1] = (_Float16)p0[1];
            af[2] = (_Float16)p0[2]; af[3] = (_Float16)p0[3];
            af[4] = (_Float16)p1[0]; af[5] = (_Float16)p1[1];
            af[6] = (_Float16)p1[2]; af[7] = (_Float16)p1[3];
            const v8h bf = *(const v8h*)(vp + s * 128 + kk * 32);
            if (kk & 1) O1 = __builtin_amdgcn_mfma_f32_16x16x32_f16(af, bf, O1, 0, 0, 0);
            else        O0 = __builtin_amdgcn_mfma_f32_16x16x32_f16(af, bf, O0, 0, 0, 0);
        }
        // write next slab into the other buffer
        if (s < 7) {
            #pragma unroll
            for (int kt2 = 0; kt2 < 2; ++kt2)
                #pragma unroll
                for (int r = 0; r < 4; ++r)
                    Ps[(pb ^ 4224) + (wg * 16 + q4 * 4 + r) * 132 + kt2 * 64 + wl * 16 + c0] =
                        S[(s + 1) * 2 + kt2][r] * inv[r];
            lgkm0();
            raw_sync();
        }
    }
    const int b = bh / H_, h = bh % H_;
    #pragma unroll
    for (int r = 0; r < 4; ++r)
        oah[((size_t)b * N_ + mt * 32 + wg * 16 + q4 * 4 + r) * C_ + h * D_ + wl * 16 + c0] =
            (_Float16)(O0[r] + O1[r]);
}

// ---------------------------------------------------------------------------
// K4: out = oah[8192,768] @ wph[768,768]^T + bias, fp32 out (nontemporal).
// (unchanged)
// ---------------------------------------------------------------------------
__global__ __launch_bounds__(256) void gemm_proj(const _Float16* __restrict__ X,
                                                 const _Float16* __restrict__ W,
                                                 const float* __restrict__ Bias,
                                                 float* __restrict__ out) {
    __shared__ _Float16 As[2 * 128 * 32];
    __shared__ _Float16 Bs[2 * 128 * 32];
    const int t = threadIdx.x;
    const int w = t >> 6, l = t & 63;
    const int q4 = l >> 4, c0 = l & 15;
    const int wm = w & 1, wn = w >> 1;
    const int m0 = blockIdx.x * 128, n0 = blockIdx.y * 128;
    const int sc8 = (t & 3) * 8;
    const int srow = t >> 2;
    v4f acc[4][4] = {};
    #pragma unroll
    for (int i = 0; i < 2; ++i) {
        const int row = i * 64 + srow;
        gload_lds16(&X[(size_t)(m0 + row) * C_ + sc8], &As[(i * 256 + t) * 8]);
        gload_lds16(&W[(size_t)(n0 + row) * C_ + sc8], &Bs[(i * 256 + t) * 8]);
    }
    __syncthreads();
    int cb = 0;
    for (int k0 = 0; k0 < C_; k0 += 32, cb ^= 1) {
        if (k0 + 32 < C_) {
            const int nb = cb ^ 1;
            #pragma unroll
            for (int i = 0; i < 2; ++i) {
                const int row = i * 64 + srow;
                gload_lds16(&X[(size_t)(m0 + row) * C_ + k0 + 32 + sc8],
                            &As[(nb * 512 + i * 256 + t) * 8]);
                gload_lds16(&W[(size_t)(n0 + row) * C_ + k0 + 32 + sc8],
                            &Bs[(nb * 512 + i * 256 + t) * 8]);
            }
        }
        v8h a[4], b[4];
        #pragma unroll
        for (int mi = 0; mi < 4; ++mi)
            a[mi] = *(const v8h*)&As[cb * 4096 + (wm * 64 + mi * 16 + c0) * 32 + q4 * 8];
        #pragma unroll
        for (int ni = 0; ni < 4; ++ni)
            b[ni] = *(const v8h*)&Bs[cb * 4096 + (wn * 64 + ni * 16 + c0) * 32 + q4 * 8];
        #pragma unroll
        for (int mi = 0; mi < 4; ++mi)
            #pragma unroll
            for (int ni = 0; ni < 4; ++ni)
                acc[mi][ni] = __builtin_amdgcn_mfma_f32_16x16x32_f16(a[mi], b[ni], acc[mi][ni], 0, 0, 0);
        __syncthreads();
    }
    #pragma unroll
    for (int ni = 0; ni < 4; ++ni) {
        const int n = n0 + wn * 64 + ni * 16 + c0;
        const float bias = Bias[n];
        #pragma unroll
        for (int mi = 0; mi < 4; ++mi) {
            #pragma unroll
            for (int r = 0; r < 4; ++r) {
                const int m = m0 + wm * 64 + mi * 16 + q4 * 4 + r;
                __builtin_nontemporal_store(acc[mi][ni][r] + bias, &out[(size_t)m * C_ + n]);
            }
        }
    }
}

extern "C" void kernel_launch(void* const* d_in, const int* in_sizes, int n_in,
                              void* d_out, int out_size, void* d_ws, size_t ws_size,
                              hipStream_t stream) {
    const float* x      = (const float*)d_in[0];
    const float* w_qkv  = (const float*)d_in[1];
    const float* w_proj = (const float*)d_in[2];
    const float* b_proj = (const float*)d_in[3];

    float* out  = (float*)d_out;                 // [8,1024,768]
    float* attn = out + (size_t)B_ * N_ * C_;    // [8,12,1024,1024]

    const size_t NX  = (size_t)B_ * N_ * C_;
    const size_t NWQ = (size_t)3 * C_ * C_;
    const size_t NWP = (size_t)C_ * C_;
    _Float16* xh  = (_Float16*)d_ws;
    _Float16* wqh = xh + NX;
    _Float16* wph = wqh + NWQ;
    _Float16* qh  = wph + NWP;
    _Float16* kh  = qh + NX;
    _Float16* vth = kh + NX;
    _Float16* oah = vth + NX;

    cast_f2h<<<dim3((int)(NX / 8 / 256)), 256, 0, stream>>>(x, xh, (int)(NX / 8));
    cast_f2h<<<dim3((int)(NWQ / 8 / 256)), 256, 0, stream>>>(w_qkv, wqh, (int)(NWQ / 8));
    cast_f2h<<<dim3((int)(NWP / 8 / 256)), 256, 0, stream>>>(w_proj, wph, (int)(NWP / 8));

    gemm_qkv  <<<dim3(64, 18), 256, 0, stream>>>(xh, wqh, qh, kh, vth);
    attn_fused<<<dim3(3072), 512, 0, stream>>>(qh, kh, vth, attn, oah);
    gemm_proj <<<dim3(64, 6), 256, 0, stream>>>(oah, wph, b_proj, out);
}